// Round 2
// baseline (337.234 us; speedup 1.0000x reference)
//
#include <hip/hip_runtime.h>
#include <hip/hip_bf16.h>
#include <cstdint>

#define TSEQ 4096
#define CDIM 2048
#define HDIM 128

typedef short bf8v __attribute__((ext_vector_type(8)));  // 8 bf16 raw bits (4 VGPRs)
typedef float f4v  __attribute__((ext_vector_type(4)));

__device__ __forceinline__ unsigned short f2b(float f) {
  union { float f; unsigned u; } v; v.f = f;
  unsigned u = v.u;
  return (unsigned short)((u + 0x7fffu + ((u >> 16) & 1u)) >> 16);  // RNE
}

__device__ __forceinline__ f4v mfma16(bf8v a, bf8v b, f4v c) {
  return __builtin_amdgcn_mfma_f32_16x16x32_bf16(a, b, c, 0, 0, 0);
}

// ---------------- Kernel 1: Wq|Wk|Wv fp32 -> Wcat bf16 in B-FRAGMENT order -------
// Chunk c = ((nb*64 + kkg)*64 + lane), 8 bf16 each: value[e] = W[nb*16 + (lane&15)]
// [kkg*32 + (lane>>4)*8 + e].  proj loads these 16B chunks directly as MFMA
// B-operand fragments (no LDS staging needed — Wcat is 1.5 MB, L2-resident).
__global__ void wcat_kernel(const float* __restrict__ Wq, const float* __restrict__ Wk,
                            const float* __restrict__ Wv, unsigned short* __restrict__ Wcat) {
  int c = blockIdx.x * 256 + threadIdx.x;   // 98304 chunks total
  int lane = c & 63;
  int kkg  = (c >> 6) & 63;
  int nb   = c >> 12;                        // 0..23
  int n  = nb * 16 + (lane & 15);
  int k0 = kkg * 32 + (lane >> 4) * 8;
  const float* src;
  if (n < 128)      src = Wq + (size_t)n * CDIM + k0;
  else if (n < 256) src = Wk + (size_t)(n - 128) * CDIM + k0;
  else              src = Wv + (size_t)(n - 256) * CDIM + k0;
  float4 f0 = ((const float4*)src)[0];
  float4 f1 = ((const float4*)src)[1];
  bf8v o;
  o[0] = (short)f2b(f0.x); o[1] = (short)f2b(f0.y);
  o[2] = (short)f2b(f0.z); o[3] = (short)f2b(f0.w);
  o[4] = (short)f2b(f1.x); o[5] = (short)f2b(f1.y);
  o[6] = (short)f2b(f1.z); o[7] = (short)f2b(f1.w);
  *(bf8v*)(Wcat + (size_t)c * 8) = o;
}

// ---------------- Kernel 2: proj GEMM v5 — barrier-free, cache-fed ---------------
// 256 blocks x 64 rows (A read once; A is L3-resident anyway), 512 thr / 8 waves.
// Wave = (substrip sub = w&3 -> rows sub*16.., colgroup cg = w>>2 -> cols cg*192..).
// A fragments loaded per-wave directly from global fp32 (32 B/lane, full 128 B
// lines; col-group pair dedups via L1/L2) and converted in-register. B fragments
// loaded directly from Wcat (fragment-ordered, coalesced 1 KB/instr, L2-hit).
// NO LDS, NO barriers in the main loop -> no vmcnt(0) barrier-drain stalls.
// LDS only for the epilogue C-tile; output layouts identical to verified v4.
__global__ __launch_bounds__(512, 2) void proj_gemm(const float* __restrict__ A,
                                                    const unsigned short* __restrict__ Bw,
                                                    unsigned short* __restrict__ QB,
                                                    unsigned short* __restrict__ KA,
                                                    unsigned short* __restrict__ VB) {
  __shared__ unsigned short Ct[64][392];  // 49 KB, epilogue only
  const int m0 = blockIdx.x * 64;
  const int tid = threadIdx.x;
  const int lane = tid & 63;
  const int w = tid >> 6;
  const int sub = w & 3;        // row substrip: rows sub*16 .. sub*16+15
  const int cg  = w >> 2;       // col group: cols cg*192 .. cg*192+191
  const int llo = lane & 15, lhi = lane >> 4;

  f4v acc[12];
#pragma unroll
  for (int j = 0; j < 12; ++j) acc[j] = (f4v){0.f, 0.f, 0.f, 0.f};

  // A: lane reads its own fragment bytes: row m0+sub*16+llo, k = it*64 + kk*32 + lhi*8
  const float* ap = A + (size_t)(m0 + sub * 16 + llo) * CDIM + lhi * 8;

  // depth-1 register prefetch of the A fragment data (4 float4 = 8 floats x 2 kk)
  float4 fa00 = *(const float4*)(ap);
  float4 fa01 = *(const float4*)(ap + 4);
  float4 fa10 = *(const float4*)(ap + 32);
  float4 fa11 = *(const float4*)(ap + 36);

  const unsigned short* bbase = Bw + (size_t)(cg * 12) * 64 * 64 * 8 + (size_t)lane * 8;

  for (int it = 0; it < 32; ++it) {
    // convert prefetched A -> bf16 fragments
    bf8v af[2];
    af[0][0] = (short)f2b(fa00.x); af[0][1] = (short)f2b(fa00.y);
    af[0][2] = (short)f2b(fa00.z); af[0][3] = (short)f2b(fa00.w);
    af[0][4] = (short)f2b(fa01.x); af[0][5] = (short)f2b(fa01.y);
    af[0][6] = (short)f2b(fa01.z); af[0][7] = (short)f2b(fa01.w);
    af[1][0] = (short)f2b(fa10.x); af[1][1] = (short)f2b(fa10.y);
    af[1][2] = (short)f2b(fa10.z); af[1][3] = (short)f2b(fa10.w);
    af[1][4] = (short)f2b(fa11.x); af[1][5] = (short)f2b(fa11.y);
    af[1][6] = (short)f2b(fa11.z); af[1][7] = (short)f2b(fa11.w);
    if (it < 31) {
      const float* apn = ap + (it + 1) * 64;
      fa00 = *(const float4*)(apn);
      fa01 = *(const float4*)(apn + 4);
      fa10 = *(const float4*)(apn + 32);
      fa11 = *(const float4*)(apn + 36);
    }
#pragma unroll
    for (int kk = 0; kk < 2; ++kk) {
      const int kkg = it * 2 + kk;
      bf8v bf[12];
#pragma unroll
      for (int j = 0; j < 12; ++j)
        bf[j] = *(const bf8v*)(bbase + ((size_t)j * 64 + kkg) * 64 * 8);
#pragma unroll
      for (int j = 0; j < 12; ++j) acc[j] = mfma16(af[kk], bf[j], acc[j]);
    }
  }

  // ---- epilogue: stage 64x384 C tile in LDS, then emit the verified layouts ----
#pragma unroll
  for (int j = 0; j < 12; ++j)
#pragma unroll
    for (int r = 0; r < 4; ++r)
      Ct[sub * 16 + lhi * 4 + r][cg * 192 + j * 16 + llo] = f2b(acc[j][r]);
  __syncthreads();

  // Q (cols 0..127) and K (cols 128..255): A-fragment layout (verbatim from v4)
  {
    const size_t base16 = (size_t)(m0 >> 4);
#pragma unroll
    for (int yy = 0; yy < 2; ++yy) {
      unsigned short* dst = yy ? KA : QB;
      const int colb = yy * 128;
#pragma unroll
      for (int p = 0; p < 2; ++p) {
        int g = p * 512 + tid;
        int t16l = g >> 8, kk2 = (g >> 6) & 3, ln = g & 63;
        int lo = ln & 15, hi = ln >> 4;
        bf8v v = *(const bf8v*)&Ct[t16l * 16 + lo][colb + kk2 * 32 + hi * 8];
        *(bf8v*)(dst + (((base16 + t16l) * 4 + kk2) * 64 + ln) * 8) = v;
      }
    }
  }
  // V (cols 256..383): transposed B-fragment layout + ones column (ht=8)
  {
    const size_t base32 = (size_t)(m0 >> 5);
#pragma unroll
    for (int p = 0; p < 3; ++p) {
      int g = p * 512 + tid;
      if (g < 1152) {
        int jbl = g / 576;
        int ht  = (g % 576) >> 6;
        int ln  = g & 63;
        int lo = ln & 15, hi = ln >> 4;
        bf8v v;
        if (ht == 8) {
#pragma unroll
          for (int e = 0; e < 8; ++e) v[e] = (lo == 0) ? (short)0x3F80 : (short)0;
        } else {
#pragma unroll
          for (int e = 0; e < 8; ++e) v[e] = (short)Ct[jbl * 32 + hi * 8 + e][256 + ht * 16 + lo];
        }
        *(bf8v*)(VB + (((base32 + jbl) * 9 + ht) * 512 + (size_t)ln * 8)) = v;
      }
    }
  }
}

// ---------------- Kernel 3: flash attention v6 — software-pipelined, no spills -----
// (unchanged)
__global__ __launch_bounds__(256, 4) void attn6(const unsigned short* __restrict__ QB,
                                                const unsigned short* __restrict__ KA,
                                                const unsigned short* __restrict__ VB,
                                                float* __restrict__ out) {
  __shared__ union SM {
    unsigned short Ps[4][2][16][68];                      // [wave][buf][row][col] 17.4 KB
    struct { float Om[4][16][68]; float Lm[4][16]; } mg;  // 17.7 KB
  } sm;
  const int x = blockIdx.x;
  const int b = x & 3;
  const int u = x >> 2;
  const int g = u >> 6, r0 = u & 63;
  const int s = (g & 1) ? (g * 64 + 63 - r0) : (g * 64 + r0);
  const int lastjt = s >> 2;
  const int tid = threadIdx.x;
  const int w = tid >> 6, lane = tid & 63;
  const int llo = lane & 15, lhi = lane >> 4;
  const float scale = 0.022097086912079608f;  // 2048^-0.5

  bf8v aK[4];
  {
    const unsigned short* kp = KA + (size_t)(b * 256 + s) * 2048;
#pragma unroll
    for (int kk = 0; kk < 4; ++kk) aK[kk] = *(const bf8v*)(kp + (kk * 64 + lane) * 8);
  }

  f4v Oacc[9];
#pragma unroll
  for (int nt = 0; nt < 9; ++nt) Oacc[nt] = (f4v){0.f, 0.f, 0.f, 0.f};

  auto computeS = [&](int jtS, int buf) {
    const unsigned short* qp = QB + (size_t)(b * 256 + jtS * 4) * 2048;
#pragma unroll
    for (int ct = 0; ct < 4; ++ct) {
      f4v acc = (f4v){0.f, 0.f, 0.f, 0.f};
#pragma unroll
      for (int kk = 0; kk < 4; ++kk) {
        bf8v bq = *(const bf8v*)(qp + ((ct * 4 + kk) * 64 + lane) * 8);
        acc = mfma16(aK[kk], bq, acc);
      }
#pragma unroll
      for (int r = 0; r < 4; ++r) {
        float sv = acc[r];
        if (jtS == lastjt) {
          int j = jtS * 64 + ct * 16 + llo;
          int i = s * 16 + lhi * 4 + r;
          if (j > i) sv = -3.0e38f;
        }
        sm.Ps[w][buf][lhi * 4 + r][ct * 16 + llo] = f2b(__expf(sv * scale));
      }
    }
  };

  if (w <= lastjt) computeS(w, 0);
  int buf = 0;
  for (int jt = w; jt <= lastjt; jt += 4) {
    bf8v aP0 = *(const bf8v*)&sm.Ps[w][buf][llo][lhi * 8];
    bf8v aP1 = *(const bf8v*)&sm.Ps[w][buf][llo][32 + lhi * 8];
    if (jt + 4 <= lastjt) computeS(jt + 4, buf ^ 1);
    const unsigned short* vp = VB + (size_t)(b * 128 + jt * 2) * 4608;  // 9 ht * 512
#pragma unroll
    for (int nt = 0; nt < 9; ++nt) {
      f4v o = Oacc[nt];
      o = mfma16(aP0, *(const bf8v*)(vp + nt * 512 + (size_t)lane * 8), o);
      o = mfma16(aP1, *(const bf8v*)(vp + 4608 + nt * 512 + (size_t)lane * 8), o);
      Oacc[nt] = o;
    }
    buf ^= 1;
  }

#pragma unroll
  for (int half = 0; half < 2; ++half) {
    __syncthreads();
#pragma unroll
    for (int nt = 0; nt < 4; ++nt)
#pragma unroll
      for (int r = 0; r < 4; ++r)
        sm.mg.Om[w][lhi * 4 + r][nt * 16 + llo] = Oacc[half * 4 + nt][r];
    if (half == 0 && llo == 0) {
#pragma unroll
      for (int r = 0; r < 4; ++r) sm.mg.Lm[w][lhi * 4 + r] = Oacc[8][r];
    }
    __syncthreads();
    {
      int row = tid >> 4, c0 = (tid & 15) * 4;
      float L = sm.mg.Lm[0][row] + sm.mg.Lm[1][row] + sm.mg.Lm[2][row] + sm.mg.Lm[3][row];
      float inv = 1.0f / L;
      float* op = out + (size_t)(b * TSEQ + s * 16 + row) * HDIM + half * 64 + c0;
#pragma unroll
      for (int e = 0; e < 4; ++e) {
        float o = sm.mg.Om[0][row][c0 + e] + sm.mg.Om[1][row][c0 + e] +
                  sm.mg.Om[2][row][c0 + e] + sm.mg.Om[3][row][c0 + e];
        op[e] = o * inv;
      }
    }
  }
}

extern "C" void kernel_launch(void* const* d_in, const int* in_sizes, int n_in,
                              void* d_out, int out_size, void* d_ws, size_t ws_size,
                              hipStream_t stream) {
  const float* idx = (const float*)d_in[0];
  const float* Wq  = (const float*)d_in[1];
  const float* Wk  = (const float*)d_in[2];
  const float* Wv  = (const float*)d_in[3];
  float* out = (float*)d_out;
  char* ws = (char*)d_ws;
  unsigned short* Wcat = (unsigned short*)ws;                        // 1.57 MB
  unsigned short* QB   = (unsigned short*)(ws + ((size_t)2  << 20)); // 4.2 MB
  unsigned short* KA   = (unsigned short*)(ws + ((size_t)7  << 20)); // 4.2 MB
  unsigned short* VB   = (unsigned short*)(ws + ((size_t)12 << 20)); // 4.72 MB

  wcat_kernel<<<384, 256, 0, stream>>>(Wq, Wk, Wv, Wcat);
  proj_gemm<<<256, 512, 0, stream>>>(idx, Wcat, QB, KA, VB);
  attn6<<<1024, 256, 0, stream>>>(QB, KA, VB, out);
}

// Round 3
// 286.161 us; speedup vs baseline: 1.1785x; 1.1785x over previous
//
#include <hip/hip_runtime.h>
#include <hip/hip_bf16.h>
#include <cstdint>

#define TSEQ 4096
#define CDIM 2048
#define HDIM 128

typedef short bf8v __attribute__((ext_vector_type(8)));  // 8 bf16 raw bits (4 VGPRs)
typedef float f4v  __attribute__((ext_vector_type(4)));

__device__ __forceinline__ unsigned short f2b(float f) {
  union { float f; unsigned u; } v; v.f = f;
  unsigned u = v.u;
  return (unsigned short)((u + 0x7fffu + ((u >> 16) & 1u)) >> 16);  // RNE
}

__device__ __forceinline__ f4v mfma16(bf8v a, bf8v b, f4v c) {
  return __builtin_amdgcn_mfma_f32_16x16x32_bf16(a, b, c, 0, 0, 0);
}

__device__ __forceinline__ void gload_lds16(const void* g, void* l) {
  __builtin_amdgcn_global_load_lds(
      (const __attribute__((address_space(1))) unsigned int*)g,
      (__attribute__((address_space(3))) unsigned int*)l, 16, 0, 0);
}

// ---------------- Kernel 1: Wq|Wk|Wv fp32 -> Wcat bf16 [384][2048] (row-major) ----
__global__ void wcat_kernel(const float* __restrict__ Wq, const float* __restrict__ Wk,
                            const float* __restrict__ Wv, unsigned short* __restrict__ Wcat) {
  int e = (blockIdx.x * 256 + threadIdx.x) * 4;
  int n = e >> 11;
  int k = e & 2047;
  const float* src;
  if (n < 128)      src = Wq + (size_t)n * CDIM + k;
  else if (n < 256) src = Wk + (size_t)(n - 128) * CDIM + k;
  else              src = Wv + (size_t)(n - 256) * CDIM + k;
  float4 f = *(const float4*)src;
  ushort4 o;
  o.x = f2b(f.x); o.y = f2b(f.y); o.z = f2b(f.z); o.w = f2b(f.w);
  *(ushort4*)(Wcat + e) = o;
}

// ---------------- Kernel 2: proj GEMM v6 — v3 grid/sync x v4 staging -------------
// Grid (256,3): block = 64 rows x 128 cols (y picks Q/K/V), 512 thr / 8 waves of
// 32x32, BK=64.  LDS 50.4 KB -> 3 blocks/CU (6 waves/SIMD): co-resident blocks
// overlap each other's barrier drains (the v4 killer at 1 block/CU).
// B staged via global_load_lds(16B) with XOR-granule swizzle (v4-verified:
// dest slot s of row r holds source granule s^(r&7); read at ((kk*4+lhi)^(llo&7))
// -> 2-way max on ds_read_b128, free).  A reg-staged fp32->bf16, pad-72 (2-way, free).
__global__ __launch_bounds__(512, 6) void proj_gemm(const float* __restrict__ A,
                                                    const unsigned short* __restrict__ Bw,
                                                    unsigned short* __restrict__ QB,
                                                    unsigned short* __restrict__ KA,
                                                    unsigned short* __restrict__ VB) {
  __shared__ union {
    struct { unsigned short As[2][64][72]; unsigned short Bs[2][128][64]; } st;  // 50.4 KB
    unsigned short Ct[64][132];                                                  // 16.9 KB
  } sm;
  const int m0 = blockIdx.x * 64;
  const int y  = blockIdx.y;          // 0=q, 1=k, 2=v
  const int n0g = y * 128;
  const int tid = threadIdx.x;
  const int lane = tid & 63;
  const int w = tid >> 6;
  const int wm = (w & 1) * 32, wn = (w >> 1) * 32;
  const int llo = lane & 15, lhi = lane >> 4;

  f4v acc[2][2];
#pragma unroll
  for (int i = 0; i < 2; ++i)
#pragma unroll
    for (int j = 0; j < 2; ++j) acc[i][j] = (f4v){0.f, 0.f, 0.f, 0.f};

  // A staging: 2 float4 per thread (64x64 fp32 = 1024 granules / 512 thr)
  const int ar0 = tid >> 4;           // 0..31
  const int ac0 = (tid & 15) * 4;     // 0..60
  const float* aptr0 = A + (size_t)(m0 + ar0) * CDIM + ac0;
  const float* aptr1 = A + (size_t)(m0 + 32 + ar0) * CDIM + ac0;

  // B staging: 2 gload_lds per wave (16 rows of 64 bf16 = 128 granules).
  // lane -> row +(lane>>3), slot lane&7 holding source granule (lane&7)^(lane>>3).
  const int brow = lane >> 3;
  const int bgs  = (lane & 7) ^ brow;
  const unsigned short* bptr = Bw + (size_t)(n0g + w * 16 + brow) * CDIM + bgs * 8;

  // ---- prologue: stage K-tile 0 into buf 0 ----
  float4 fa0 = *(const float4*)(aptr0);
  float4 fa1 = *(const float4*)(aptr1);
  gload_lds16(bptr,            &sm.st.Bs[0][w * 16][0]);
  gload_lds16(bptr + 8 * CDIM, &sm.st.Bs[0][w * 16 + 8][0]);
  {
    ushort4 o0, o1;
    o0.x = f2b(fa0.x); o0.y = f2b(fa0.y); o0.z = f2b(fa0.z); o0.w = f2b(fa0.w);
    o1.x = f2b(fa1.x); o1.y = f2b(fa1.y); o1.z = f2b(fa1.z); o1.w = f2b(fa1.w);
    *(ushort4*)&sm.st.As[0][ar0][ac0]      = o0;
    *(ushort4*)&sm.st.As[0][32 + ar0][ac0] = o1;
  }

  for (int it = 0; it < 32; ++it) {
    const int cur = it & 1;
    __syncthreads();
    if (it < 31) {
      fa0 = *(const float4*)(aptr0 + (it + 1) * 64);
      fa1 = *(const float4*)(aptr1 + (it + 1) * 64);
      const int nxt = cur ^ 1;
      gload_lds16(bptr + (it + 1) * 64,            &sm.st.Bs[nxt][w * 16][0]);
      gload_lds16(bptr + 8 * CDIM + (it + 1) * 64, &sm.st.Bs[nxt][w * 16 + 8][0]);
    }
#pragma unroll
    for (int kk = 0; kk < 2; ++kk) {
      bf8v af[2], bfr[2];
      af[0] = *(const bf8v*)&sm.st.As[cur][wm + llo][kk * 32 + lhi * 8];
      af[1] = *(const bf8v*)&sm.st.As[cur][wm + 16 + llo][kk * 32 + lhi * 8];
      const int bofs = (((kk << 2) + lhi) ^ (llo & 7)) * 8;
      bfr[0] = *(const bf8v*)&sm.st.Bs[cur][wn + llo][bofs];
      bfr[1] = *(const bf8v*)&sm.st.Bs[cur][wn + 16 + llo][bofs];
#pragma unroll
      for (int i = 0; i < 2; ++i)
#pragma unroll
        for (int j = 0; j < 2; ++j) acc[i][j] = mfma16(af[i], bfr[j], acc[i][j]);
    }
    if (it < 31) {
      const int nxt = cur ^ 1;
      ushort4 o0, o1;
      o0.x = f2b(fa0.x); o0.y = f2b(fa0.y); o0.z = f2b(fa0.z); o0.w = f2b(fa0.w);
      o1.x = f2b(fa1.x); o1.y = f2b(fa1.y); o1.z = f2b(fa1.z); o1.w = f2b(fa1.w);
      *(ushort4*)&sm.st.As[nxt][ar0][ac0]      = o0;
      *(ushort4*)&sm.st.As[nxt][32 + ar0][ac0] = o1;
    }
  }
  __syncthreads();
#pragma unroll
  for (int i = 0; i < 2; ++i)
#pragma unroll
    for (int j = 0; j < 2; ++j)
#pragma unroll
      for (int r = 0; r < 4; ++r)
        sm.Ct[wm + i * 16 + lhi * 4 + r][wn + j * 16 + llo] = f2b(acc[i][j][r]);
  __syncthreads();
  if (y < 2) {
    unsigned short* dst = (y == 0) ? QB : KA;
    const size_t base16 = (size_t)(m0 >> 4);
#pragma unroll
    for (int p = 0; p < 2; ++p) {
      int g = p * 512 + tid;
      int t16l = g >> 8, kk = (g >> 6) & 3, ln = g & 63;
      int lo = ln & 15, hi = ln >> 4;
      bf8v v = *(const bf8v*)&sm.Ct[t16l * 16 + lo][kk * 32 + hi * 8];
      *(bf8v*)(dst + (((base16 + t16l) * 4 + kk) * 64 + ln) * 8) = v;
    }
  } else {
    const size_t base32 = (size_t)(m0 >> 5);
#pragma unroll
    for (int p = 0; p < 3; ++p) {
      int g = p * 512 + tid;
      if (g < 1152) {
        int jbl = g / 576;
        int ht  = (g % 576) >> 6;
        int ln  = g & 63;
        int lo = ln & 15, hi = ln >> 4;
        bf8v v;
        if (ht == 8) {
#pragma unroll
          for (int e = 0; e < 8; ++e) v[e] = (lo == 0) ? (short)0x3F80 : (short)0;
        } else {
#pragma unroll
          for (int e = 0; e < 8; ++e) v[e] = (short)sm.Ct[jbl * 32 + hi * 8 + e][ht * 16 + lo];
        }
        *(bf8v*)(VB + (((base32 + jbl) * 9 + ht) * 512 + (size_t)ln * 8)) = v;
      }
    }
  }
}

// ---------------- Kernel 3: flash attention v6 — software-pipelined, no spills -----
// (unchanged)
__global__ __launch_bounds__(256, 4) void attn6(const unsigned short* __restrict__ QB,
                                                const unsigned short* __restrict__ KA,
                                                const unsigned short* __restrict__ VB,
                                                float* __restrict__ out) {
  __shared__ union SM {
    unsigned short Ps[4][2][16][68];                      // [wave][buf][row][col] 17.4 KB
    struct { float Om[4][16][68]; float Lm[4][16]; } mg;  // 17.7 KB
  } sm;
  const int x = blockIdx.x;
  const int b = x & 3;
  const int u = x >> 2;
  const int g = u >> 6, r0 = u & 63;
  const int s = (g & 1) ? (g * 64 + 63 - r0) : (g * 64 + r0);
  const int lastjt = s >> 2;
  const int tid = threadIdx.x;
  const int w = tid >> 6, lane = tid & 63;
  const int llo = lane & 15, lhi = lane >> 4;
  const float scale = 0.022097086912079608f;  // 2048^-0.5

  bf8v aK[4];
  {
    const unsigned short* kp = KA + (size_t)(b * 256 + s) * 2048;
#pragma unroll
    for (int kk = 0; kk < 4; ++kk) aK[kk] = *(const bf8v*)(kp + (kk * 64 + lane) * 8);
  }

  f4v Oacc[9];
#pragma unroll
  for (int nt = 0; nt < 9; ++nt) Oacc[nt] = (f4v){0.f, 0.f, 0.f, 0.f};

  auto computeS = [&](int jtS, int buf) {
    const unsigned short* qp = QB + (size_t)(b * 256 + jtS * 4) * 2048;
#pragma unroll
    for (int ct = 0; ct < 4; ++ct) {
      f4v acc = (f4v){0.f, 0.f, 0.f, 0.f};
#pragma unroll
      for (int kk = 0; kk < 4; ++kk) {
        bf8v bq = *(const bf8v*)(qp + ((ct * 4 + kk) * 64 + lane) * 8);
        acc = mfma16(aK[kk], bq, acc);
      }
#pragma unroll
      for (int r = 0; r < 4; ++r) {
        float sv = acc[r];
        if (jtS == lastjt) {
          int j = jtS * 64 + ct * 16 + llo;
          int i = s * 16 + lhi * 4 + r;
          if (j > i) sv = -3.0e38f;
        }
        sm.Ps[w][buf][lhi * 4 + r][ct * 16 + llo] = f2b(__expf(sv * scale));
      }
    }
  };

  if (w <= lastjt) computeS(w, 0);
  int buf = 0;
  for (int jt = w; jt <= lastjt; jt += 4) {
    bf8v aP0 = *(const bf8v*)&sm.Ps[w][buf][llo][lhi * 8];
    bf8v aP1 = *(const bf8v*)&sm.Ps[w][buf][llo][32 + lhi * 8];
    if (jt + 4 <= lastjt) computeS(jt + 4, buf ^ 1);
    const unsigned short* vp = VB + (size_t)(b * 128 + jt * 2) * 4608;  // 9 ht * 512
#pragma unroll
    for (int nt = 0; nt < 9; ++nt) {
      f4v o = Oacc[nt];
      o = mfma16(aP0, *(const bf8v*)(vp + nt * 512 + (size_t)lane * 8), o);
      o = mfma16(aP1, *(const bf8v*)(vp + 4608 + nt * 512 + (size_t)lane * 8), o);
      Oacc[nt] = o;
    }
    buf ^= 1;
  }

#pragma unroll
  for (int half = 0; half < 2; ++half) {
    __syncthreads();
#pragma unroll
    for (int nt = 0; nt < 4; ++nt)
#pragma unroll
      for (int r = 0; r < 4; ++r)
        sm.mg.Om[w][lhi * 4 + r][nt * 16 + llo] = Oacc[half * 4 + nt][r];
    if (half == 0 && llo == 0) {
#pragma unroll
      for (int r = 0; r < 4; ++r) sm.mg.Lm[w][lhi * 4 + r] = Oacc[8][r];
    }
    __syncthreads();
    {
      int row = tid >> 4, c0 = (tid & 15) * 4;
      float L = sm.mg.Lm[0][row] + sm.mg.Lm[1][row] + sm.mg.Lm[2][row] + sm.mg.Lm[3][row];
      float inv = 1.0f / L;
      float* op = out + (size_t)(b * TSEQ + s * 16 + row) * HDIM + half * 64 + c0;
#pragma unroll
      for (int e = 0; e < 4; ++e) {
        float o = sm.mg.Om[0][row][c0 + e] + sm.mg.Om[1][row][c0 + e] +
                  sm.mg.Om[2][row][c0 + e] + sm.mg.Om[3][row][c0 + e];
        op[e] = o * inv;
      }
    }
  }
}

extern "C" void kernel_launch(void* const* d_in, const int* in_sizes, int n_in,
                              void* d_out, int out_size, void* d_ws, size_t ws_size,
                              hipStream_t stream) {
  const float* idx = (const float*)d_in[0];
  const float* Wq  = (const float*)d_in[1];
  const float* Wk  = (const float*)d_in[2];
  const float* Wv  = (const float*)d_in[3];
  float* out = (float*)d_out;
  char* ws = (char*)d_ws;
  unsigned short* Wcat = (unsigned short*)ws;                        // 1.57 MB
  unsigned short* QB   = (unsigned short*)(ws + ((size_t)2  << 20)); // 4.2 MB
  unsigned short* KA   = (unsigned short*)(ws + ((size_t)7  << 20)); // 4.2 MB
  unsigned short* VB   = (unsigned short*)(ws + ((size_t)12 << 20)); // 4.72 MB

  wcat_kernel<<<768, 256, 0, stream>>>(Wq, Wk, Wv, Wcat);
  proj_gemm<<<dim3(256, 3), 512, 0, stream>>>(idx, Wcat, QB, KA, VB);
  attn6<<<1024, 256, 0, stream>>>(QB, KA, VB, out);
}